// Round 13
// baseline (1544.105 us; speedup 1.0000x reference)
//
#include <hip/hip_runtime.h>
#include <hip/hip_bf16.h>
#include <math.h>

// Problem constants (fixed by the reference)
#define Nn 50000
#define Ee 400000
#define Gg 2000
#define NPGc 25
#define Hc 128
#define Lc 5
#define M2c 50048              // branch row padding (64-aligned)
#define R2c 100096             // 2 * M2c
#define GPB 50                 // nodes per block = 2 graphs (1000 g2 per branch)

typedef __attribute__((ext_vector_type(8))) short short8;   // 8 bf16 = 4 VGPRs
typedef __attribute__((ext_vector_type(4))) float fx4;      // MFMA accumulator

__device__ inline short bf16r(float x){
  unsigned u = __float_as_uint(x);
  unsigned r = (u + 0x7fffu + ((u >> 16) & 1u)) >> 16;
  return (short)r;
}
__device__ inline float lo16f(int p){
  return __uint_as_float(((unsigned)p) << 16);
}
__device__ inline float hi16f(int p){
  return __uint_as_float(((unsigned)p) & 0xffff0000u);
}
__device__ inline int pack2(float a, float b){
  return (int)(((unsigned)(unsigned short)bf16r(a)) |
               (((unsigned)(unsigned short)bf16r(b)) << 16));
}

// ------------------------------------------------------------------
// Graph preprocessing
// ------------------------------------------------------------------
__global__ void deg_kernel(const int* __restrict__ dst, int* __restrict__ deg, int E){
  int i = blockIdx.x * blockDim.x + threadIdx.x;
  if (i < E) atomicAdd(&deg[dst[i]], 1);
}

__global__ void scan1_kernel(const int* __restrict__ deg, int* __restrict__ part,
                             int* __restrict__ bsums, int n){
  __shared__ int tmp[1024];
  int b = blockIdx.x, t = threadIdx.x;
  int i = b * 1024 + t;
  int v = (i < n) ? deg[i] : 0;
  tmp[t] = v;
  __syncthreads();
  for (int off = 1; off < 1024; off <<= 1){
    int add = (t >= off) ? tmp[t - off] : 0;
    __syncthreads();
    tmp[t] += add;
    __syncthreads();
  }
  part[i] = tmp[t];
  if (t == 1023) bsums[b] = tmp[1023];
}
__global__ void scan2_kernel(int* __restrict__ bsums, int nb){
  if (threadIdx.x == 0){
    int s = 0;
    for (int i = 0; i < nb; i++){ s += bsums[i]; bsums[i] = s; }
  }
}
__global__ void scan3_kernel(const int* __restrict__ part, const int* __restrict__ bsums,
                             int* __restrict__ rowstart, int n){
  int i = blockIdx.x * blockDim.x + threadIdx.x;
  if (i == 0) rowstart[0] = 0;
  if (i < n){
    int b = i >> 10;
    int base = b ? bsums[b - 1] : 0;
    rowstart[i + 1] = part[i] + base;
  }
}

__global__ void copy_int_kernel(const int* __restrict__ a, int* __restrict__ b, int n){
  int i = blockIdx.x * blockDim.x + threadIdx.x;
  if (i < n) b[i] = a[i];
}

__global__ void scatter_kernel(const int* __restrict__ src, const int* __restrict__ dst,
                               const int* __restrict__ ef, int* cursor,
                               int* __restrict__ src_srt, int* __restrict__ code_srt, int E){
  int i = blockIdx.x * blockDim.x + threadIdx.x;
  if (i >= E) return;
  int p = atomicAdd(&cursor[dst[i]], 1);
  src_srt[p] = src[i];
  code_srt[p] = ef[i * 3 + 0] * 25 + ef[i * 3 + 1] * 5 + ef[i * 3 + 2];
}

__global__ void ampatt_kernel(const int* __restrict__ deg, float* __restrict__ amp,
                              float* __restrict__ att, int n){
  int i = blockIdx.x * blockDim.x + threadIdx.x;
  if (i >= n) return;
  if (i >= Nn){ amp[i] = 0.f; att[i] = 0.f; return; }
  float d = (float)deg[i];
  float ld = logf(d + 1.0f);
  amp[i] = ld;
  att[i] = (deg[i] > 0) ? (1.0f / ld) : 0.0f;
}

// ------------------------------------------------------------------
// Node embedding, BOTH branches stacked
// ------------------------------------------------------------------
__global__ void embed2_kernel(const int* __restrict__ nf,
                              const float* __restrict__ aemb_f,
                              const float* __restrict__ aemb_t,
                              float* __restrict__ h, short* __restrict__ h16){
  int idx = blockIdx.x * blockDim.x + threadIdx.x;
  if (idx >= R2c * Hc) return;
  int n = idx >> 7, c = idx & 127;
  int br = n >= M2c;
  int local = n - br * M2c;
  if (local >= Nn){ h[idx] = 0.f; h16[idx] = 0; return; }
  const float* aemb = br ? aemb_t : aemb_f;
  float s = 0.f;
#pragma unroll
  for (int f = 0; f < 9; f++){
    int row = nf[local * 9 + f] + 16 * f;
    s += aemb[row * Hc + c];
  }
  h[idx] = s;
  h16[idx] = bf16r(s);
}

// bsum2[b][code][c]: 125 distinct edge embeddings, both branches
__global__ void bsum2_kernel(const float* __restrict__ bemb_f, const float* __restrict__ bemb_t,
                             float* __restrict__ bsum2){
  int idx = blockIdx.x * blockDim.x + threadIdx.x;
  if (idx >= 2 * 125 * Hc) return;
  int b = idx / (125 * Hc);
  int rem = idx % (125 * Hc);
  int code = rem >> 7, c = rem & 127;
  int e0 = code / 25, e1 = (code / 5) % 5, e2 = code % 5;
  const float* bemb = b ? bemb_t : bemb_f;
  bsum2[idx] = bemb[e0 * Hc + c] + bemb[(5 + e1) * Hc + c] + bemb[(10 + e2) * Hc + c];
}

// ------------------------------------------------------------------
// up-front weight converts, both branches x 5 layers
// ------------------------------------------------------------------
__global__ void conv_pre_all_kernel(const float* __restrict__ wpre_f,
                                    const float* __restrict__ wpre_t,
                                    short* __restrict__ btpre_all){
  int idx = blockIdx.x * blockDim.x + threadIdx.x;
  if (idx >= 2 * Lc * 256 * 128) return;
  int bl = idx / (256 * 128);
  int rem = idx % (256 * 128);
  int col = rem >> 7, k = rem & 127;
  int b = bl / Lc, l = bl % Lc;
  const float* wl = (b ? wpre_t : wpre_f) + (size_t)l * 384 * 128;
  float v = (col < 128) ? wl[k * 128 + col] : wl[(128 + k) * 128 + (col - 128)];
  btpre_all[(size_t)bl * 256 * 128 + col * 128 + k] = bf16r(v);
}
__global__ void conv_post_all_kernel(const float* __restrict__ wpost_f,
                                     const float* __restrict__ wpost_t,
                                     short* __restrict__ btpost_all){
  int idx = blockIdx.x * blockDim.x + threadIdx.x;
  if (idx >= 2 * Lc * 1664 * 128) return;
  int bl = idx / (1664 * 128);
  int rem = idx % (1664 * 128);
  int k = rem >> 7, c = rem & 127;
  int b = bl / Lc, l = bl % Lc;
  const float* wl = (b ? wpost_t : wpost_f) + (size_t)l * 1664 * 128;
  btpost_all[(size_t)bl * 128 * 1664 + (size_t)c * 1664 + k] = bf16r(wl[(size_t)k * 128 + c]);
}

// ezt16_all[bl][code][c] (bf16) = bsum2[b][code][:] @ W_e[b,l] + b_pre[b,l]
__global__ void ezt_all_kernel(const float* __restrict__ wpre_f, const float* __restrict__ wpre_t,
                               const float* __restrict__ bpre_f, const float* __restrict__ bpre_t,
                               const float* __restrict__ bsum2, short* __restrict__ ezt16_all){
  int code = blockIdx.x;
  int bl   = blockIdx.y;
  int t = threadIdx.x;
  int b = bl / Lc, l = bl % Lc;
  const float* wl = (b ? wpre_t : wpre_f) + (size_t)l * 384 * 128 + 256 * 128;
  const float* bp = (b ? bpre_t : bpre_f) + (size_t)l * 128;
  __shared__ float bs[128];
  bs[t] = bsum2[((size_t)b * 125 + code) * 128 + t];
  __syncthreads();
  float acc = bp[t];
#pragma unroll 8
  for (int k = 0; k < 128; k++) acc += bs[k] * wl[k * 128 + t];
  ezt16_all[((size_t)bl * 125 + code) * 128 + t] = bf16r(acc);
}

// ------------------------------------------------------------------
// Graph readout (merged): block b*Gg+g -> branch b, graph g
// ------------------------------------------------------------------
__global__ void readout2_kernel(const float* __restrict__ h,
                                float* __restrict__ r3, float* __restrict__ r2){
  int bi = blockIdx.x;
  int br = bi >= Gg;
  int g = bi - br * Gg;
  int c = threadIdx.x;
  float mn = 3.402823466e38f, mx = -3.402823466e38f, s = 0.f;
  const float* hp = h + ((size_t)br * M2c + (size_t)g * NPGc) * Hc + c;
#pragma unroll
  for (int i = 0; i < NPGc; i++){
    float v = hp[i * Hc];
    mn = fminf(mn, v); mx = fmaxf(mx, v); s += v;
  }
  float* r = br ? r2 : r3;
  r[(size_t)g * 384 + c]       = mn;
  r[(size_t)g * 384 + 128 + c] = mx;
  r[(size_t)g * 384 + 256 + c] = s * (1.0f / NPGc);
}

// ------------------------------------------------------------------
// Fused head, one graph per block
// ------------------------------------------------------------------
__global__ __launch_bounds__(256)
void head_kernel(const float* __restrict__ r2, const float* __restrict__ r3,
                 const float* __restrict__ w_out3, const float* __restrict__ b_out3,
                 const float* __restrict__ w1, const float* __restrict__ b1,
                 const float* __restrict__ w2, const float* __restrict__ b2,
                 float* __restrict__ out)
{
  __shared__ float r3_s[384];
  __shared__ float x_s[640];
  __shared__ float h1_s[128];
  __shared__ float partial[256];
  int g = blockIdx.x, t = threadIdx.x;

  for (int i = t; i < 384; i += 256){
    float v2 = r2[(size_t)g * 384 + i];
    r3_s[i] = r3[(size_t)g * 384 + i];
    x_s[i] = v2;
  }
  __syncthreads();
  {
    float acc = b_out3[t];
#pragma unroll 8
    for (int k = 0; k < 384; k++) acc += r3_s[k] * w_out3[k * 256 + t];
    x_s[384 + t] = acc;
  }
  __syncthreads();
  {
    int c = t & 127, half = t >> 7;
    float acc = half ? 0.f : b1[c];
    int kb = half * 320;
#pragma unroll 8
    for (int k = kb; k < kb + 320; k++) acc += x_s[k] * w1[k * 128 + c];
    partial[t] = acc;
  }
  __syncthreads();
  if (t < 128) h1_s[t] = fmaxf(partial[t] + partial[t + 128], 0.f);
  __syncthreads();
  {
    int c = t & 127, half = t >> 7;
    float acc = half ? 0.f : b2[c];
    int kb = half * 64;
#pragma unroll 8
    for (int k = kb; k < kb + 64; k++) acc += h1_s[k] * w2[k * 128 + c];
    partial[t] = acc;
  }
  __syncthreads();
  if (t < 128) out[(size_t)g * 128 + t] = partial[t] + partial[t + 128];
}

// ------------------------------------------------------------------
// layer_fused: ONE kernel per GNN layer. Block = 2 whole graphs
// (50 nodes, padded to 64 rows) of one branch; 512 threads = 8 waves.
// Phase A: pretrans hsd = h16 @ W_pre (K=128,N=256) -> LDS (never global)
// Phase B: PNA stats, LDS-local gathers (edges stay within the graphs),
//          stats kept in REGISTERS (thread computes exactly the 16
//          channels it later stages: {kof..kof+8} U {64+kof..+8})
// Phase C: post GEMM K=1664 (slot-decode As/Bs aliasing the dead hsd
//          LDS); A k<128 from global h16, k>=128 from packed stat regs
//          with amp/att scaling. Epilogue: +bias +resid -> h, h16.
// LDS: union( hsd 64x132 ints = 33792B , As 8KB + Bs 16KB ).
// ------------------------------------------------------------------
__global__ __launch_bounds__(512, 4)
void layer_fused_kernel(const short* __restrict__ h16g,
                        const float* __restrict__ hres,
                        const short* __restrict__ pre0, const short* __restrict__ pre1,
                        const short* __restrict__ post0, const short* __restrict__ post1,
                        const float* __restrict__ bias0, const float* __restrict__ bias1,
                        const int* __restrict__ ez0, const int* __restrict__ ez1,
                        const int* __restrict__ src_srt, const int* __restrict__ code_srt,
                        const int* __restrict__ rowstart,
                        const float* __restrict__ amp, const float* __restrict__ att,
                        float* __restrict__ hout, short* __restrict__ h16out)
{
  __shared__ int smem[8448];               // 33792 B union
  short* hsdS = (short*)smem;              // [64][264 shorts] (132 ints, %32==4)
  int*   hsdI = smem;
  short8* AsS = (short8*)smem;             // 512 slots (phase C)
  short8* BsS = (short8*)(smem + 2048);    // 1024 slots

  int tid = threadIdx.x;
  int br = blockIdx.x / 1000;
  int g2 = blockIdx.x % 1000;
  int rowbase = br * M2c + g2 * GPB;
  const short* pre  = br ? pre1 : pre0;
  const short* post = br ? post1 : post0;
  const float* bias = br ? bias1 : bias0;
  const int* ez16 = br ? ez1 : ez0;

  int w = tid >> 6, ln = tid & 63;
  int lo = ln & 15, q = ln >> 4;
  int lo_t = tid & 15, q_t = (tid >> 4) & 3, rq = (tid >> 6) & 3;
  int node = rq * 16 + lo_t;               // row this thread owns (stats+A-staging)
  int kof = (tid >> 8) * 32 + q_t * 8;     // its 8-aligned k-offset

  // ======== phase A: pretrans -> hsd LDS ========
  {
    int rt = w & 3, colh = w >> 2;
    fx4 acc2[8];
#pragma unroll
    for (int ct = 0; ct < 8; ct++) acc2[ct] = (fx4){0.f, 0.f, 0.f, 0.f};
    const short* ap = h16g + (size_t)(rowbase + rt * 16 + lo) * 128;
#pragma unroll
    for (int ks = 0; ks < 4; ks++){
      short8 af = *(const short8*)(ap + ks * 32 + q * 8);
#pragma unroll
      for (int ct = 0; ct < 8; ct++){
        short8 bf = *(const short8*)(pre + (colh * 128 + ct * 16 + lo) * 128 + ks * 32 + q * 8);
        acc2[ct] = __builtin_amdgcn_mfma_f32_16x16x32_bf16(af, bf, acc2[ct], 0, 0, 0);
      }
    }
#pragma unroll
    for (int ct = 0; ct < 8; ct++)
#pragma unroll
      for (int r = 0; r < 4; r++)
        hsdS[(rt * 16 + q * 4 + r) * 264 + colh * 128 + ct * 16 + lo] = bf16r(acc2[ct][r]);
  }
  __syncthreads();

  // ======== phase B: stats (registers) ========
  float ampv = 0.f, attv = 0.f;
  int pk[32];
#pragma unroll
  for (int i = 0; i < 32; i++) pk[i] = 0;
  if (node < GPB){
    int gn = g2 * GPB + node;
    int e0 = rowstart[gn], e1 = rowstart[gn + 1];
    if (e1 > e0){
      ampv = amp[gn]; attv = att[gn];
      int ko2 = kof >> 1;
      float hd[16];
#pragma unroll
      for (int i = 0; i < 4; i++){
        int p = hsdI[node * 132 + 64 + ko2 + i];
        hd[2*i] = lo16f(p); hd[2*i+1] = hi16f(p);
        int p2 = hsdI[node * 132 + 96 + ko2 + i];
        hd[8 + 2*i] = lo16f(p2); hd[9 + 2*i] = hi16f(p2);
      }
      float sum[16], sq[16], mx[16], mn[16];
#pragma unroll
      for (int j = 0; j < 16; j++){
        sum[j] = 0.f; sq[j] = 0.f; mx[j] = -3.402823466e38f; mn[j] = 3.402823466e38f;
      }
      int sl = src_srt[e0] - g2 * GPB;
      int cd = code_srt[e0];
      for (int k = e0; k < e1; k++){
        int hb = sl * 132;
        const int* ep = ez16 + cd * 64;
        int hp[8], ee[8];
#pragma unroll
        for (int i = 0; i < 4; i++){
          hp[i]   = hsdI[hb + ko2 + i];
          hp[4+i] = hsdI[hb + 32 + ko2 + i];
          ee[i]   = ep[ko2 + i];
          ee[4+i] = ep[32 + ko2 + i];
        }
        int k2 = (k + 1 < e1) ? k + 1 : k;
        sl = src_srt[k2] - g2 * GPB;
        cd = code_srt[k2];
#pragma unroll
        for (int i = 0; i < 8; i++){
          float z0 = lo16f(hp[i]) + hd[2*i]   + lo16f(ee[i]);
          float z1 = hi16f(hp[i]) + hd[2*i+1] + hi16f(ee[i]);
          sum[2*i]   += z0; sq[2*i]   += z0 * z0;
          mx[2*i]   = fmaxf(mx[2*i], z0);   mn[2*i]   = fminf(mn[2*i], z0);
          sum[2*i+1] += z1; sq[2*i+1] += z1 * z1;
          mx[2*i+1] = fmaxf(mx[2*i+1], z1); mn[2*i+1] = fminf(mn[2*i+1], z1);
        }
      }
      float d = (float)(e1 - e0);
#pragma unroll
      for (int j = 0; j < 16; j++){
        float m = sum[j] / d;
        float v = sq[j] / d - m * m; v = v > 0.f ? v : 0.f;
        sum[j] = m;                       // mean in place
        sq[j] = sqrtf(v + 1e-5f);         // std in place
      }
      // pack: group jl: stat = jl>>1 (mean,max,min,std), halfblock = jl&1
#pragma unroll
      for (int jl = 0; jl < 8; jl++){
#pragma unroll
        for (int ii = 0; ii < 4; ii++){
          int i = (jl & 1) * 4 + ii;
          float a, b;
          if ((jl >> 1) == 0){ a = sum[2*i]; b = sum[2*i+1]; }
          else if ((jl >> 1) == 1){ a = mx[2*i]; b = mx[2*i+1]; }
          else if ((jl >> 1) == 2){ a = mn[2*i]; b = mn[2*i+1]; }
          else { a = sq[2*i]; b = sq[2*i+1]; }
          pk[jl * 4 + ii] = pack2(a, b);
        }
      }
    }
  }
  // (first barrier of phase C protects hsd until all stats reads done)

  // ======== phase C: post GEMM K=1664 ========
  {
    const int K = 1664;
    int rt2 = w >> 1, ch2 = w & 1;
    fx4 acc[4];
#pragma unroll
    for (int c4 = 0; c4 < 4; c4++) acc[c4] = (fx4){0.f, 0.f, 0.f, 0.f};

    int scol = ((tid >> 6) & 7) * 16 + (tid & 15);
    int skA = ((tid >> 4) & 3) * 8;
    const short* BtL = post + (size_t)scol * K;
    const short* h16A = h16g + (size_t)(rowbase + node) * 128;

    short8 ra, rb0, rb1;
    ra  = *(const short8*)(h16A + kof);
    rb0 = *(const short8*)(BtL + skA);
    rb1 = *(const short8*)(BtL + 32 + skA);

    // chunks 0,1: A from h16
#pragma unroll
    for (int c = 0; c < 2; c++){
      __syncthreads();
      AsS[tid] = ra;
      BsS[tid] = rb0; BsS[tid + 512] = rb1;
      __syncthreads();
      int kn = 64 * (c + 1);
      if (c == 0) ra = *(const short8*)(h16A + 64 + kof);
      rb0 = *(const short8*)(BtL + kn + skA);
      rb1 = *(const short8*)(BtL + kn + 32 + skA);
      short8 a0 = AsS[rt2 * 64 + ln];
      short8 a1 = AsS[256 + rt2 * 64 + ln];
#pragma unroll
      for (int c4 = 0; c4 < 4; c4++){
        int ct = ch2 * 4 + c4;
        short8 b0 = BsS[ct * 64 + ln];
        short8 b1 = BsS[512 + ct * 64 + ln];
        acc[c4] = __builtin_amdgcn_mfma_f32_16x16x32_bf16(a0, b0, acc[c4], 0, 0, 0);
        acc[c4] = __builtin_amdgcn_mfma_f32_16x16x32_bf16(a1, b1, acc[c4], 0, 0, 0);
      }
    }
    // 3 sections x 8 groups: A from packed stats
    for (int sec = 0; sec < 3; sec++){
      float sc = (sec == 0) ? 1.f : ((sec == 1) ? ampv : attv);
#pragma unroll
      for (int jl = 0; jl < 8; jl++){
        __syncthreads();
        {
          int vv[4];
#pragma unroll
          for (int ii = 0; ii < 4; ii++){
            int p = pk[jl * 4 + ii];
            vv[ii] = (sec == 0) ? p : pack2(lo16f(p) * sc, hi16f(p) * sc);
          }
          AsS[tid] = *(short8*)vv;
        }
        BsS[tid] = rb0; BsS[tid + 512] = rb1;
        __syncthreads();
        int cidx = 2 + sec * 8 + jl;
        if (cidx < 25){
          int kn = 64 * (cidx + 1);
          rb0 = *(const short8*)(BtL + kn + skA);
          rb1 = *(const short8*)(BtL + kn + 32 + skA);
        }
        short8 a0 = AsS[rt2 * 64 + ln];
        short8 a1 = AsS[256 + rt2 * 64 + ln];
#pragma unroll
        for (int c4 = 0; c4 < 4; c4++){
          int ct = ch2 * 4 + c4;
          short8 b0 = BsS[ct * 64 + ln];
          short8 b1 = BsS[512 + ct * 64 + ln];
          acc[c4] = __builtin_amdgcn_mfma_f32_16x16x32_bf16(a0, b0, acc[c4], 0, 0, 0);
          acc[c4] = __builtin_amdgcn_mfma_f32_16x16x32_bf16(a1, b1, acc[c4], 0, 0, 0);
        }
      }
    }

    // epilogue (rows >= GPB are padding -> not written)
#pragma unroll
    for (int r = 0; r < 4; r++){
      int row = rt2 * 16 + q * 4 + r;
      if (row < GPB){
        size_t grow = (size_t)(rowbase + row);
#pragma unroll
        for (int c4 = 0; c4 < 4; c4++){
          int col = (ch2 * 4 + c4) * 16 + lo;
          float v = acc[c4][r] + bias[col] + hres[grow * 128 + col];
          hout[grow * 128 + col] = v;
          h16out[grow * 128 + col] = bf16r(v);
        }
      }
    }
  }
}

// ------------------------------------------------------------------
extern "C" void kernel_launch(void* const* d_in, const int* in_sizes, int n_in,
                              void* d_out, int out_size, void* d_ws, size_t ws_size,
                              hipStream_t stream)
{
  const int*   node_feat = (const int*)  d_in[0];
  const int*   edge_feat = (const int*)  d_in[1];
  const int*   src       = (const int*)  d_in[2];
  const int*   dst       = (const int*)  d_in[3];
  const float* aemb_f  = (const float*) d_in[5];
  const float* bemb_f  = (const float*) d_in[6];
  const float* w_pre_f = (const float*) d_in[7];
  const float* b_pre_f = (const float*) d_in[8];
  const float* w_post_f= (const float*) d_in[9];
  const float* b_post_f= (const float*) d_in[10];
  const float* w_out3  = (const float*) d_in[11];
  const float* b_out3  = (const float*) d_in[12];
  const float* aemb    = (const float*) d_in[13];
  const float* bemb    = (const float*) d_in[14];
  const float* w_pre   = (const float*) d_in[15];
  const float* b_pre   = (const float*) d_in[16];
  const float* w_post  = (const float*) d_in[17];
  const float* b_post  = (const float*) d_in[18];
  const float* w1      = (const float*) d_in[19];
  const float* b1      = (const float*) d_in[20];
  const float* w2      = (const float*) d_in[21];
  const float* b2      = (const float*) d_in[22];
  float* out = (float*)d_out;

  // ---- workspace carve ----
  char* w = (char*)d_ws;
  auto carve = [&](size_t bytes) -> void* {
    void* p = (void*)w;
    w += (bytes + 255) & ~(size_t)255;
    return p;
  };
  float* h_a       = (float*)carve((size_t)R2c * Hc * 4);
  float* h_b       = (float*)carve((size_t)R2c * Hc * 4);
  short* h16_a     = (short*)carve((size_t)R2c * Hc * 2);
  short* h16_b     = (short*)carve((size_t)R2c * Hc * 2);
  short* btpre_all = (short*)carve((size_t)2 * Lc * 256 * 128 * 2);
  short* btpost_all= (short*)carve((size_t)2 * Lc * 128 * 1664 * 2);
  float* bsum2     = (float*)carve((size_t)2 * 125 * Hc * 4);
  short* ezt16_all = (short*)carve((size_t)2 * Lc * 125 * Hc * 2);
  float* amp       = (float*)carve((size_t)M2c * 4);
  float* att       = (float*)carve((size_t)M2c * 4);
  float* r3        = (float*)carve((size_t)Gg * 384 * 4);
  float* r2        = (float*)carve((size_t)Gg * 384 * 4);
  int* deg      = (int*)carve((size_t)Nn * 4);
  int* rowstart = (int*)carve((size_t)(Nn + 1) * 4);
  int* cursor   = (int*)carve((size_t)Nn * 4);
  int* part     = (int*)carve((size_t)50176 * 4);
  int* bsums    = (int*)carve((size_t)64 * 4);
  int* src_srt  = (int*)carve((size_t)Ee * 4);
  int* code_srt = (int*)carve((size_t)Ee * 4);

  // ---- graph preprocessing ----
  hipMemsetAsync(deg, 0, (size_t)Nn * 4, stream);
  deg_kernel<<<(Ee + 255) / 256, 256, 0, stream>>>(dst, deg, Ee);
  scan1_kernel<<<49, 1024, 0, stream>>>(deg, part, bsums, Nn);
  scan2_kernel<<<1, 64, 0, stream>>>(bsums, 49);
  scan3_kernel<<<(Nn + 255) / 256, 256, 0, stream>>>(part, bsums, rowstart, Nn);
  copy_int_kernel<<<(Nn + 255) / 256, 256, 0, stream>>>(rowstart, cursor, Nn);
  scatter_kernel<<<(Ee + 255) / 256, 256, 0, stream>>>(src, dst, edge_feat, cursor,
                                                       src_srt, code_srt, Ee);
  ampatt_kernel<<<(M2c + 255) / 256, 256, 0, stream>>>(deg, amp, att, M2c);

  // ---- up-front shared tables ----
  bsum2_kernel<<<(2 * 125 * Hc + 255) / 256, 256, 0, stream>>>(bemb_f, bemb, bsum2);
  conv_pre_all_kernel<<<(2 * Lc * 256 * 128 + 255) / 256, 256, 0, stream>>>(
      w_pre_f, w_pre, btpre_all);
  conv_post_all_kernel<<<(2 * Lc * 1664 * 128 + 255) / 256, 256, 0, stream>>>(
      w_post_f, w_post, btpost_all);
  ezt_all_kernel<<<dim3(125, 2 * Lc), 128, 0, stream>>>(
      w_pre_f, w_pre, b_pre_f, b_pre, bsum2, ezt16_all);

  // ---- merged-branch GNN: one fused kernel per layer ----
  float* h_cur = h_a;   float* h_nxt = h_b;
  short* g_cur = h16_a; short* g_nxt = h16_b;
  embed2_kernel<<<(R2c * Hc + 255) / 256, 256, 0, stream>>>(
      node_feat, aemb_f, aemb, h_cur, g_cur);

  for (int l = 0; l < Lc; l++){
    const short* pre0 = btpre_all + (size_t)(0 * Lc + l) * 256 * 128;
    const short* pre1 = btpre_all + (size_t)(1 * Lc + l) * 256 * 128;
    const short* post0 = btpost_all + (size_t)(0 * Lc + l) * 128 * 1664;
    const short* post1 = btpost_all + (size_t)(1 * Lc + l) * 128 * 1664;
    const int* ez0 = (const int*)(ezt16_all + (size_t)(0 * Lc + l) * 125 * Hc);
    const int* ez1 = (const int*)(ezt16_all + (size_t)(1 * Lc + l) * 125 * Hc);
    const float* bp0 = b_post_f + (size_t)l * 128;
    const float* bp1 = b_post   + (size_t)l * 128;

    layer_fused_kernel<<<2000, 512, 0, stream>>>(
        g_cur, h_cur, pre0, pre1, post0, post1, bp0, bp1,
        ez0, ez1, src_srt, code_srt, rowstart, amp, att,
        h_nxt, g_nxt);

    { float* t = h_cur; h_cur = h_nxt; h_nxt = t; }
    { short* t = g_cur; g_cur = g_nxt; g_nxt = t; }
  }

  readout2_kernel<<<2 * Gg, 128, 0, stream>>>(h_cur, r3, r2);
  head_kernel<<<Gg, 256, 0, stream>>>(r2, r3, w_out3, b_out3, w1, b1, w2, b2, out);
}